// Round 3
// baseline (79.014 us; speedup 1.0000x reference)
//
#include <hip/hip_runtime.h>

// FingerprintPool: B=64, A=32, C=64, SEG_LENS=(1,167,512), F_fp=679.
// Math reduction (biases cancel in both softmaxes):
//   d_i[b,a] = x[b,a]·w_inner[i]; e_i[b,a] = x[b,a]·w_inter[i]
//   attn(l): softmax of d_i over hit set of column l
//   sc2[b,l] = sum_hit ed*e / Z  (excluded if column empty)
//   a2: softmax of sc2 over l within segment
//   out[b,c] = sum_a x[b,a,c] * sum_i ed_i[a]*H_i[a],
//     H_i[a] = sum_{l in seg i, hit(l,a)} a2[l]/Z_l,  ed = exp(d - dmax_i), Z_l = sum_hit ed.
//
// R3: issue order w -> x -> fp (vmcnt is in-order, so the x_s store waits at
// vmcnt(32), leaving fp in flight through phases 1-2); mask assembly deferred
// to phase 3 (first use); w staged via LDS so phase 1 doesn't eat a cold HBM miss.

constexpr int NB    = 64;
constexpr int NA    = 32;
constexpr int NC    = 64;
constexpr int NFP   = 679;   // fp columns (without the implicit ones column)
constexpr int LTOT  = 680;   // 1 + 167 + 512
constexpr int S1    = 1;     // seg1 start
constexpr int S2    = 168;   // seg2 start
constexpr int NT    = 1024;  // threads per block (16 waves)
constexpr int NCHK  = 32;    // phase-5 chunks
constexpr int CHKW  = 22;    // ceil(680/32)

__global__ __launch_bounds__(NT) void fpool_kernel(
    const float* __restrict__ x,        // (2048, 64)
    const int*   __restrict__ fp,       // (2048, 679)
    const float* __restrict__ w_inner,  // (3, 64)
    const float* __restrict__ w_inter,  // (3, 64)
    float*       __restrict__ out)      // (64, 64)
{
    __shared__ float    x_s[NA][NC + 1];     // +1 pad: conflict-free both axes
    __shared__ float    w_s[6][NC];          // [0..2]=w_inner, [3..5]=w_inter
    __shared__ float    ed_s[3][NA];         // exp(d - dmax)
    __shared__ float    fe_s[3][NA];         // ed * e
    __shared__ unsigned mask_s[LTOT];
    __shared__ float    Z_s[LTOT];
    __shared__ float    sc2_s[LTOT];
    __shared__ float    coef_s[LTOT];        // a2[l]/Z_l (0 for empty columns)
    __shared__ float    part_s[NCHK][96];    // phase-5 partials [chunk][i*32+a]
    __shared__ float    Gsum_s[NA];

    const int tid = threadIdx.x;
    const int b   = blockIdx.x;
    const int l   = tid;

    // ---- issue loads in order of first use: w, x, fp ----
    float wv = 0.f;
    if (tid < 384) wv = (tid < 192) ? w_inner[tid] : w_inter[tid - 192];

    const float* xb = x + (size_t)b * NA * NC;
    const float  x0 = xb[tid];
    const float  x1 = xb[tid + NT];

    int v[NA];                                // fp row slice; mask built lazily
    if (l >= 1 && l < LTOT) {
        const int* f = fp + (size_t)b * NA * NFP + (l - 1);
        #pragma unroll
        for (int a = 0; a < NA; ++a) v[a] = f[(size_t)a * NFP];
    }

    // ---- LDS stores (each waits only on its own producer's vmcnt slot) ----
    if (tid < 384) ((float*)w_s)[tid] = wv;   // flat layout matches [6][64]
    x_s[tid >> 6][tid & 63] = x0;
    { const int i1 = tid + NT; x_s[i1 >> 6][i1 & 63] = x1; }
    if (tid < NA) Gsum_s[tid] = 0.f;
    __syncthreads();

    // ---- phase 1: d,e dots + group-max + ed/fe (96 threads, LDS-only reads) ----
    if (tid < 96) {
        const int i = tid >> 5, a = tid & 31;
        float dacc = 0.f, eacc = 0.f;
        #pragma unroll
        for (int c = 0; c < NC; ++c) {
            const float xv = x_s[a][c];
            dacc += xv * w_s[i][c];       // broadcast within 32-group
            eacc += xv * w_s[3 + i][c];
        }
        float mx = dacc;                  // max over aligned 32-lane group
        #pragma unroll
        for (int o = 16; o; o >>= 1) mx = fmaxf(mx, __shfl_xor(mx, o));
        const float ed = __expf(dacc - mx);
        ed_s[i][a] = ed;
        fe_s[i][a] = ed * eacc;
    }
    __syncthreads();

    // ---- phase 3: assemble mask from still-in-flight registers; Z, sc2 ----
    if (l < LTOT) {
        unsigned m = 0xFFFFFFFFu;
        if (l >= 1) {
            m = 0u;
            #pragma unroll
            for (int a = 0; a < NA; ++a) m |= (v[a] != 0) ? (1u << a) : 0u;
        }
        const int i = (l >= S2) ? 2 : ((l >= S1) ? 1 : 0);
        float Z = 0.f, P = 0.f;
        #pragma unroll
        for (int a = 0; a < NA; ++a) {
            const float bit = (float)((m >> a) & 1u);
            Z += bit * ed_s[i][a];
            P += bit * fe_s[i][a];
        }
        mask_s[l] = m;
        Z_s[l]    = Z;
        sc2_s[l]  = m ? (P / Z) : -1e30f;
    }
    __syncthreads();

    // ---- phase 4: softmax over l per segment (3 waves) ----
    {
        const int wave = tid >> 6, lane = tid & 63;
        if (wave < 3) {
            const int s = (wave == 0) ? 0 : (wave == 1 ? S1 : S2);
            const int e = (wave == 0) ? S1 : (wave == 1 ? S2 : LTOT);
            float mx = -3e38f;
            for (int ll = s + lane; ll < e; ll += 64) mx = fmaxf(mx, sc2_s[ll]);
            #pragma unroll
            for (int o = 32; o; o >>= 1) mx = fmaxf(mx, __shfl_xor(mx, o));
            float sm = 0.f;
            for (int ll = s + lane; ll < e; ll += 64) sm += __expf(sc2_s[ll] - mx);
            #pragma unroll
            for (int o = 32; o; o >>= 1) sm += __shfl_xor(sm, o);
            const float inv = 1.f / sm;
            for (int ll = s + lane; ll < e; ll += 64) {
                const unsigned mm = mask_s[ll];
                coef_s[ll] = mm ? (__expf(sc2_s[ll] - mx) * inv / Z_s[ll]) : 0.f;
            }
        }
    }
    __syncthreads();

    // ---- phase 5: H_i[a] partials, 32 chunks x (3x32) ----
    {
        const int a = tid & 31, chunk = tid >> 5;   // chunk in [0,32)
        const int ls = chunk * CHKW;
        const int le = (ls + CHKW < LTOT) ? ls + CHKW : LTOT;
        float h0 = 0.f, h1 = 0.f, h2 = 0.f;
        for (int ll = ls; ll < le; ++ll) {
            const float cf = coef_s[ll] * (float)((mask_s[ll] >> a) & 1u);
            if (ll >= S2)      h2 += cf;
            else if (ll >= S1) h1 += cf;
            else               h0 += cf;
        }
        part_s[chunk][a]      = h0;
        part_s[chunk][32 + a] = h1;
        part_s[chunk][64 + a] = h2;
    }
    __syncthreads();

    // ---- phase 5b: reduce partials, fold into Gsum ----
    if (tid < 96) {
        float s = 0.f;
        #pragma unroll
        for (int c = 0; c < NCHK; ++c) s += part_s[c][tid];
        const int i = tid >> 5, a = tid & 31;
        atomicAdd(&Gsum_s[a], ed_s[i][a] * s);
    }
    __syncthreads();

    // ---- phase 6: out[b,c] = sum_a Gsum[a] * x[b,a,c] ----
    if (tid < NC) {
        float acc = 0.f;
        #pragma unroll
        for (int a = 0; a < NA; ++a) acc += Gsum_s[a] * x_s[a][tid];
        out[b * NC + tid] = acc;
    }
}

extern "C" void kernel_launch(void* const* d_in, const int* in_sizes, int n_in,
                              void* d_out, int out_size, void* d_ws, size_t ws_size,
                              hipStream_t stream) {
    const float* x       = (const float*)d_in[0];
    // d_in[1] = batch (unused), d_in[3] = fp_length (unused)
    const int*   fp      = (const int*)d_in[2];
    const float* w_inner = (const float*)d_in[4];
    // d_in[5] = b_inner (cancels in softmax)
    const float* w_inter = (const float*)d_in[6];
    // d_in[7] = b_inter (cancels in softmax)
    float* out = (float*)d_out;

    fpool_kernel<<<NB, NT, 0, stream>>>(x, fp, w_inner, w_inter, out);
}